// Round 3
// baseline (81.471 us; speedup 1.0000x reference)
//
#include <hip/hip_runtime.h>

#define B_    32
#define CIN_  64
#define COUT_ 64
#define IMG_  128
#define W4_   (IMG_ / 4)        // 32 float4 per row
#define PIX4_ (IMG_ * W4_)      // 4096 float4 per plane
#define NPOS_ (B_ * PIX4_)      // 131072 float4 positions

// ---- Kernel A: partial channel sums. blockIdx.y = g selects channels
// [g*32, g*32+32). Pure streaming reads (134 MB), tiny writes (4 MB). ----
__global__ __launch_bounds__(256) void ch_sum_kernel(const float* __restrict__ x,
                                                     float* __restrict__ ws) {
    const int g = blockIdx.y;                      // 0..1 channel group
    int i = blockIdx.x * 256 + threadIdx.x;        // 0..NPOS_-1 (exact)
    int b = i >> 12;                               // / PIX4_
    int p = i & (PIX4_ - 1);
    const float4* xp = reinterpret_cast<const float4*>(x)
                     + (size_t)b * CIN_ * PIX4_ + (size_t)g * 32 * PIX4_ + p;
    float4 acc = make_float4(0.f, 0.f, 0.f, 0.f);
#pragma unroll 8
    for (int c = 0; c < 32; ++c) {
        float4 v = xp[(size_t)c * PIX4_];
        acc.x += v.x; acc.y += v.y; acc.z += v.z; acc.w += v.w;
    }
    reinterpret_cast<float4*>(ws)[(size_t)g * NPOS_ + i] = acc;
}

// ---- Kernel B: each thread owns (b,h,w4); reads its 3x6 stencil from the
// two partial planes (L2-resident, ~19 MB), computes all 64 couts in
// registers, streams 64 float4 stores. Store-bound. ----
__global__ __launch_bounds__(256) void conv_all_couts_kernel(const float* __restrict__ ws,
                                                             const float* __restrict__ kern,
                                                             const float* __restrict__ bias,
                                                             float* __restrict__ out) {
    int i = blockIdx.x * 256 + threadIdx.x;        // 0..NPOS_-1
    int b   = i >> 12;
    int rem = i & (PIX4_ - 1);
    int h   = rem >> 5;
    int w4  = rem & 31;

    float v[3][6];
#pragma unroll
    for (int r = 0; r < 3; ++r)
#pragma unroll
        for (int j = 0; j < 6; ++j) v[r][j] = 0.f;

#pragma unroll
    for (int gidx = 0; gidx < 2; ++gidx) {
        const float* base = ws + (size_t)gidx * (NPOS_ * 4) + (size_t)b * IMG_ * IMG_;
#pragma unroll
        for (int dr = -1; dr <= 1; ++dr) {
            const int r = h + dr;
            if (r < 0 || r >= IMG_) continue;
            const float* rp = base + r * IMG_ + w4 * 4;
            float4 c = *reinterpret_cast<const float4*>(rp);
            v[dr + 1][1] += c.x; v[dr + 1][2] += c.y;
            v[dr + 1][3] += c.z; v[dr + 1][4] += c.w;
            if (w4 > 0)  v[dr + 1][0] += rp[-1];
            if (w4 < 31) v[dr + 1][5] += rp[4];
        }
    }

    float4* outp = reinterpret_cast<float4*>(out)
                 + (size_t)b * COUT_ * PIX4_ + (size_t)h * W4_ + w4;

#pragma unroll 4
    for (int co = 0; co < COUT_; ++co) {
        const float* kw = kern + co * 9;
        const float k0 = kw[0], k1 = kw[1], k2 = kw[2];
        const float k3 = kw[3], k4 = kw[4], k5 = kw[5];
        const float k6 = kw[6], k7 = kw[7], k8 = kw[8];
        const float bv = (float)CIN_ * bias[co];

        float a[4];
#pragma unroll
        for (int j = 0; j < 4; ++j) {
            a[j] = bv
                 + k0 * v[0][j] + k1 * v[0][j + 1] + k2 * v[0][j + 2]
                 + k3 * v[1][j] + k4 * v[1][j + 1] + k5 * v[1][j + 2]
                 + k6 * v[2][j] + k7 * v[2][j + 1] + k8 * v[2][j + 2];
        }
        outp[(size_t)co * PIX4_] = make_float4(a[0], a[1], a[2], a[3]);
    }
}

extern "C" void kernel_launch(void* const* d_in, const int* in_sizes, int n_in,
                              void* d_out, int out_size, void* d_ws, size_t ws_size,
                              hipStream_t stream) {
    const float* x    = (const float*)d_in[0];   // (32,64,128,128) f32
    const float* kern = (const float*)d_in[1];   // (64,3,3) f32
    const float* bias = (const float*)d_in[2];   // (64,1,1,1) f32
    float* out = (float*)d_out;                  // (32,64,128,128) f32
    float* ws  = (float*)d_ws;                   // 2 x (32,128,128) f32 = 4 MiB

    dim3 ga(NPOS_ / 256, 2);                     // (512, 2) = 1024 blocks
    ch_sum_kernel<<<ga, 256, 0, stream>>>(x, ws);

    conv_all_couts_kernel<<<dim3(NPOS_ / 256), 256, 0, stream>>>(ws, kern, bias, out);
}

// Round 4
// 76.152 us; speedup vs baseline: 1.0699x; 1.0699x over previous
//
#include <hip/hip_runtime.h>

#define B_    32
#define CIN_  64
#define COUT_ 64
#define IMG_  128
#define W4_   32                 // float4 per row
#define PIX4_ 4096               // float4 per plane
#define NPOS_ (B_ * PIX4_)       // 131072 float4 positions
#define NG_   16                 // partial groups
#define KPL_  (CIN_ / NG_)       // 4 planes per group

// ---- Kernel A: sequential-stream partial channel sums. Block = (g, b) reads
// its 4 planes (256 KiB) in memory order; 16 float4 register accumulators. ----
__global__ __launch_bounds__(256, 2) void ch_sum_partial(const float* __restrict__ x,
                                                         float* __restrict__ part) {
    const int g = blockIdx.x, b = blockIdx.y, tid = threadIdx.x;
    const float4* xp = reinterpret_cast<const float4*>(x)
                     + ((size_t)b * CIN_ + (size_t)g * KPL_) * PIX4_;
    float4 acc[16];
#pragma unroll
    for (int k = 0; k < 16; ++k) acc[k] = make_float4(0.f, 0.f, 0.f, 0.f);

#pragma unroll
    for (int c = 0; c < KPL_; ++c) {
#pragma unroll
        for (int k = 0; k < 16; ++k) {
            float4 v = xp[(size_t)c * PIX4_ + k * 256 + tid];
            acc[k].x += v.x; acc[k].y += v.y; acc[k].z += v.z; acc[k].w += v.w;
        }
    }

    float4* pp = reinterpret_cast<float4*>(part) + (size_t)g * NPOS_ + (size_t)b * PIX4_;
#pragma unroll
    for (int k = 0; k < 16; ++k) pp[k * 256 + tid] = acc[k];
}

// ---- Kernel C: xs = sum of 16 partials (L2/L3-resident, tiny). ----
__global__ __launch_bounds__(256, 4) void part_reduce(const float* __restrict__ part,
                                                      float* __restrict__ xs) {
    const int i = blockIdx.x * 256 + threadIdx.x;     // 0..NPOS_-1
    float4 s = make_float4(0.f, 0.f, 0.f, 0.f);
#pragma unroll
    for (int gg = 0; gg < NG_; ++gg) {
        float4 v = reinterpret_cast<const float4*>(part)[(size_t)gg * NPOS_ + i];
        s.x += v.x; s.y += v.y; s.z += v.z; s.w += v.w;
    }
    reinterpret_cast<float4*>(xs)[i] = s;
}

// ---- Kernel B: block = (b, co, half-plane). Stage 66 xs rows in LDS, each
// thread computes 8 consecutive rows at fixed w4 (sliding 3-row window),
// stores walk the (b,co) plane sequentially. ----
__global__ __launch_bounds__(256, 4) void conv_plane(const float* __restrict__ xs,
                                                     const float* __restrict__ kern,
                                                     const float* __restrict__ bias,
                                                     float* __restrict__ out) {
    __shared__ float t[66 * IMG_];                    // 33 KB

    // bijective XCD-chunked swizzle: nwg = 4096 = 8 * 512; co fastest so the
    // 128 blocks sharing (b) are contiguous -> same XCD's L2 holds xs[b].
    const int n   = blockIdx.x;
    const int swz = (n & 7) * 512 + (n >> 3);
    const int co   = swz & 63;
    const int half = (swz >> 6) & 1;
    const int b    = swz >> 7;
    const int tid  = threadIdx.x;
    const int r0   = half * 64;

    const float4* xsb = reinterpret_cast<const float4*>(xs) + (size_t)b * PIX4_;
    for (int pos = tid; pos < 66 * W4_; pos += 256) { // 2112 float4
        const int lr  = pos >> 5;                     // 0..65, global row r0-1+lr
        const int w4s = pos & 31;
        const int row = r0 - 1 + lr;
        float4 v = make_float4(0.f, 0.f, 0.f, 0.f);
        if (row >= 0 && row < IMG_) v = xsb[row * W4_ + w4s];
        reinterpret_cast<float4*>(t)[pos] = v;
    }
    __syncthreads();

    const float* kw = kern + co * 9;
    const float k0 = kw[0], k1 = kw[1], k2 = kw[2];
    const float k3 = kw[3], k4 = kw[4], k5 = kw[5];
    const float k6 = kw[6], k7 = kw[7], k8 = kw[8];
    const float bv = (float)CIN_ * bias[co];

    const int w4 = tid & 31;
    const int rb = (tid >> 5) * 8;                    // local output rows rb..rb+7

    float4 L[3], C[3], R[3];
    const float4* tp = reinterpret_cast<const float4*>(t);
    const float4 z4 = make_float4(0.f, 0.f, 0.f, 0.f);

#define LOAD3(slot, tr)                                                        \
    do {                                                                       \
        const float4* rowp = tp + (tr) * W4_;                                  \
        C[slot] = rowp[w4];                                                    \
        L[slot] = (w4 > 0)  ? rowp[w4 - 1] : z4;                               \
        R[slot] = (w4 < 31) ? rowp[w4 + 1] : z4;                               \
    } while (0)

    LOAD3(0, rb + 0);
    LOAD3(1, rb + 1);

    float4* outp = reinterpret_cast<float4*>(out) + (size_t)(b * COUT_ + co) * PIX4_;

#pragma unroll
    for (int j = 0; j < 8; ++j) {
        LOAD3((j + 2) % 3, rb + j + 2);
        const int st = j % 3, sm = (j + 1) % 3, sb = (j + 2) % 3;

        float4 a;
        a.x = bv + k0 * L[st].w + k1 * C[st].x + k2 * C[st].y
                 + k3 * L[sm].w + k4 * C[sm].x + k5 * C[sm].y
                 + k6 * L[sb].w + k7 * C[sb].x + k8 * C[sb].y;
        a.y = bv + k0 * C[st].x + k1 * C[st].y + k2 * C[st].z
                 + k3 * C[sm].x + k4 * C[sm].y + k5 * C[sm].z
                 + k6 * C[sb].x + k7 * C[sb].y + k8 * C[sb].z;
        a.z = bv + k0 * C[st].y + k1 * C[st].z + k2 * C[st].w
                 + k3 * C[sm].y + k4 * C[sm].z + k5 * C[sm].w
                 + k6 * C[sb].y + k7 * C[sb].z + k8 * C[sb].w;
        a.w = bv + k0 * C[st].z + k1 * C[st].w + k2 * R[st].x
                 + k3 * C[sm].z + k4 * C[sm].w + k5 * R[sm].x
                 + k6 * C[sb].z + k7 * C[sb].w + k8 * R[sb].x;

        outp[(size_t)(r0 + rb + j) * W4_ + w4] = a;
    }
#undef LOAD3
}

extern "C" void kernel_launch(void* const* d_in, const int* in_sizes, int n_in,
                              void* d_out, int out_size, void* d_ws, size_t ws_size,
                              hipStream_t stream) {
    const float* x    = (const float*)d_in[0];   // (32,64,128,128) f32
    const float* kern = (const float*)d_in[1];   // (64,3,3) f32
    const float* bias = (const float*)d_in[2];   // (64,1,1,1) f32
    float* out  = (float*)d_out;                 // (32,64,128,128) f32
    float* part = (float*)d_ws;                  // 16 x 2 MiB partials
    float* xs   = part + (size_t)NG_ * NPOS_ * 4; // +32 MiB: final xs (2 MiB)

    ch_sum_partial<<<dim3(NG_, B_), 256, 0, stream>>>(x, part);
    part_reduce<<<dim3(NPOS_ / 256), 256, 0, stream>>>(part, xs);
    conv_plane<<<dim3(B_ * COUT_ * 2), 256, 0, stream>>>(xs, kern, bias, out);
}